// Round 10
// baseline (218.860 us; speedup 1.0000x reference)
//
#include <hip/hip_runtime.h>

typedef unsigned short u16;
typedef unsigned int u32;
typedef __bf16 bf16x8 __attribute__((ext_vector_type(8)));
typedef float f4_t __attribute__((ext_vector_type(4)));

#define E_DIM 1024
#define L_TOT 4097
#define B_SZ 2
#define M_ROWS 8194   // B*L
#define NWIN 31
#define HHEADS 16
#define GCHUNKS 17    // ceil(4097/256)

__device__ __forceinline__ float b2f(u16 v) {
  union { u32 u; float f; } x; x.u = ((u32)v) << 16; return x.f;
}
__device__ __forceinline__ u16 f2b(float f) {
  union { float f; u32 u; } x; x.f = f;
  u32 r = (x.u + 0x7FFFu + ((x.u >> 16) & 1u)) >> 16;
  return (u16)r;
}
__device__ __forceinline__ f4_t mfma16(bf16x8 a, bf16x8 b, f4_t c) {
  return __builtin_amdgcn_mfma_f32_16x16x32_bf16(a, b, c, 0, 0, 0);
}
__device__ __forceinline__ u32 cvtpk(float lo, float hi) {
  u32 r;
  asm volatile("v_cvt_pk_bf16_f32 %0, %1, %2" : "=v"(r) : "v"(lo), "v"(hi));
  return r;
}

// async global->LDS, 16B per lane; LDS dest = wave-uniform base + lane*16
#define GLOAD16(gp, lp)                                                              \
  __builtin_amdgcn_global_load_lds(                                                  \
      (const __attribute__((address_space(1))) u32*)(gp),                            \
      (__attribute__((address_space(3))) u32*)(lp), 16, 0, 0)

#define WAITVM(N) asm volatile("s_waitcnt vmcnt(" #N ")" ::: "memory")
// one barrier per phase; sched_barrier after it prevents mem-op hoisting above
#define PBAR                                  \
  {                                           \
    __builtin_amdgcn_s_barrier();             \
    __builtin_amdgcn_sched_barrier(0);        \
  }

// ---------------- fp32 -> bf16 convert (hidden states) ----------------
__global__ __launch_bounds__(256) void cvt_kernel(const float* __restrict__ src,
                                                  u16* __restrict__ dst, int n4) {
  int i = blockIdx.x * 256 + threadIdx.x;
  if (i >= n4) return;
  float4 v = ((const float4*)src)[i];
  u16 o[4] = {f2b(v.x), f2b(v.y), f2b(v.z), f2b(v.w)};
  *(uint2*)(dst + (size_t)i * 4) = *(uint2*)o;
}

// ---------------- weight transpose + convert: W (K x N) -> Wt (N x K) bf16 ----------------
__global__ __launch_bounds__(256) void wtrans_kernel(const float* __restrict__ w0,
                                                     const float* __restrict__ w1,
                                                     const float* __restrict__ w2,
                                                     const float* __restrict__ w3,
                                                     u16* __restrict__ wtb) {
  const float* src = blockIdx.z == 0 ? w0 : blockIdx.z == 1 ? w1 : blockIdx.z == 2 ? w2 : w3;
  u16* dst = wtb + (size_t)blockIdx.z * E_DIM * E_DIM;
  __shared__ float tile[32][33];
  int tx = threadIdx.x, ty = threadIdx.y;
  int x = blockIdx.x * 32 + tx;
  int y0 = blockIdx.y * 32;
  for (int j = ty; j < 32; j += 8) tile[j][tx] = src[(size_t)(y0 + j) * E_DIM + x];
  __syncthreads();
  for (int j = ty; j < 32; j += 8)
    dst[(size_t)(blockIdx.x * 32 + j) * E_DIM + blockIdx.y * 32 + tx] = f2b(tile[tx][j]);
}

// ============ 256x256 8-phase GEMM, 1 barrier/phase (r10) ============
// C(M x NTIL*256) = A(M x 1024) * Wt^T + bias; Wt stored [N][1024].
// 512 thr = 8 waves (2M x 4N); per-wave out 128x64. BK=64, 2 k-halves of 32.
// LDS [2 buf][2 kh][256][4 slots of 8 u16] per operand (128 KB).
// Phase p: ds_reads; 1 half-tile stage (2 DMA); setprio(1) 16 MFMA setprio(0);
// [p3/p7 only: counted WAITVM]; s_barrier. Compiler free to pipeline lgkmcnt.
// Correctness: stage(p) targets region last read at p-1 (terminal barrier of
// p-1 protects); WAITVM(4)+barrier at p3/p7 => all waves' DMA for the tile
// about to be read has landed. Tail iter: WAITVM(0).
template <int MODE>
__device__ __forceinline__ void gemm8_body(const u16* __restrict__ A,
                                           const u16* __restrict__ Wt,
                                           const float* __restrict__ b0,
                                           const float* __restrict__ b1,
                                           const float* __restrict__ b2,
                                           void* __restrict__ outBase,
                                           int M, int NTIL) {
  constexpr int AHALF = 256 * 32;   // u16 per k-half region
  constexpr int ABUF = 2 * AHALF;   // u16 per dbuf
  __shared__ __align__(16) u16 sm[4 * ABUF];  // 128 KB
  u16* sA = sm;
  u16* sB = sm + 2 * ABUF;
  u16* epi = sm;                    // epilogue alias

  int nwg = gridDim.x;
  int q8 = nwg >> 3, r8 = nwg & 7;
  int orig = blockIdx.x;
  int xcd = orig & 7, loc = orig >> 3;
  int wg = (xcd < r8 ? xcd * (q8 + 1) : r8 * (q8 + 1) + (xcd - r8) * q8) + loc;
  int mt = wg / NTIL, nt = wg - mt * NTIL;
  int m0 = mt * 256, n0 = nt * 256;

  int t = threadIdx.x, lane = t & 63, w = t >> 6;
  int wm = w >> 2, wn = w & 3;
  int lr = lane & 15, g = lane >> 4;

  int ssrc = (((t & 3) ^ ((t >> 3) & 3)) << 3);
  const u16* paA[2];
  const u16* pbB[2];
#pragma unroll
  for (int i = 0; i < 2; i++) {
    int ra = m0 + i * 128 + (t >> 2);
    if (ra >= M) ra = M - 1;
    paA[i] = A + (size_t)ra * 1024 + ssrc;
    pbB[i] = Wt + (size_t)(n0 + i * 128 + (t >> 2)) * 1024 + ssrc;
  }
  int wb = w * 512;

#define STA(bf, kh, kt)                                                          \
  {                                                                              \
    GLOAD16(paA[0] + (kt) * 64 + (kh) * 32, sA + (bf) * ABUF + (kh) * AHALF + wb);       \
    GLOAD16(paA[1] + (kt) * 64 + (kh) * 32, sA + (bf) * ABUF + (kh) * AHALF + 4096 + wb); \
  }
#define STB(bf, kh, kt)                                                          \
  {                                                                              \
    GLOAD16(pbB[0] + (kt) * 64 + (kh) * 32, sB + (bf) * ABUF + (kh) * AHALF + wb);       \
    GLOAD16(pbB[1] + (kt) * 64 + (kh) * 32, sB + (bf) * ABUF + (kh) * AHALF + 4096 + wb); \
  }

  int swz = ((g ^ ((lr >> 1) & 3)) << 3);
  int arow0 = wm * 128 + lr;
  int brow0 = wn * 64 + lr;

#define RD_A(bf, KK, MH, mi) \
  (*(const bf16x8*)&sA[(bf) * ABUF + (KK) * AHALF + (arow0 + (MH) * 64 + (mi) * 16) * 32 + swz])
#define RD_B(bf, KK, nj) \
  (*(const bf16x8*)&sB[(bf) * ABUF + (KK) * AHALF + (brow0 + (nj) * 16) * 32 + swz])

  f4_t acc[8][4] = {};
  bf16x8 bvr0, bvr1, bvr2, bvr3;

#define MMROW(MH, mi, af)                                    \
  acc[(MH) * 4 + (mi)][0] = mfma16(af, bvr0, acc[(MH) * 4 + (mi)][0]); \
  acc[(MH) * 4 + (mi)][1] = mfma16(af, bvr1, acc[(MH) * 4 + (mi)][1]); \
  acc[(MH) * 4 + (mi)][2] = mfma16(af, bvr2, acc[(MH) * 4 + (mi)][2]); \
  acc[(MH) * 4 + (mi)][3] = mfma16(af, bvr3, acc[(MH) * 4 + (mi)][3]);

// phase: reads || stage || MFMA ; optional counted vm-wait ; terminal barrier
#define PHASE(bf, MH, KK, LOADB, STG, VMW)                   \
  {                                                          \
    bf16x8 af0 = RD_A(bf, KK, MH, 0);                        \
    bf16x8 af1 = RD_A(bf, KK, MH, 1);                        \
    bf16x8 af2 = RD_A(bf, KK, MH, 2);                        \
    bf16x8 af3 = RD_A(bf, KK, MH, 3);                        \
    if (LOADB) {                                             \
      bvr0 = RD_B(bf, KK, 0);                                \
      bvr1 = RD_B(bf, KK, 1);                                \
      bvr2 = RD_B(bf, KK, 2);                                \
      bvr3 = RD_B(bf, KK, 3);                                \
    }                                                        \
    STG;                                                     \
    __builtin_amdgcn_s_setprio(1);                           \
    MMROW(MH, 0, af0);                                       \
    MMROW(MH, 1, af1);                                       \
    MMROW(MH, 2, af2);                                       \
    MMROW(MH, 3, af3);                                       \
    __builtin_amdgcn_s_setprio(0);                           \
    VMW;                                                     \
    PBAR;                                                    \
  }

  // ---- prologue: buf0 tile0 (both halves) + buf1 tile1 k-half0 ----
  STA(0, 0, 0); STB(0, 0, 0);
  STA(0, 1, 0); STB(0, 1, 0);
  STA(1, 0, 1); STB(1, 0, 1);
  WAITVM(4);          // tile0 fully landed (per-wave)
  __builtin_amdgcn_s_barrier();  // all waves' tile0 DMA landed
  __builtin_amdgcn_sched_barrier(0);

  // ---- main loop: iters j=0..6, tiles 2j (buf0) then 2j+1 (buf1) ----
  for (int j = 0; j < 7; ++j) {
    int k1 = 2 * j + 1, k2 = 2 * j + 2, k3 = 2 * j + 3;
    PHASE(0, 0, 0, true,  STA(1, 1, k1), {});          // p0
    PHASE(0, 1, 0, false, STB(1, 1, k1), {});          // p1
    PHASE(0, 0, 1, true,  STA(0, 0, k2), {});          // p2
    PHASE(0, 1, 1, false, STB(0, 0, k2), WAITVM(4));   // p3: tile 2j+1 landed
    PHASE(1, 0, 0, true,  STA(0, 1, k2), {});          // p4
    PHASE(1, 1, 0, false, STB(0, 1, k2), {});          // p5
    PHASE(1, 0, 1, true,  STA(1, 0, k3), {});          // p6
    PHASE(1, 1, 1, false, STB(1, 0, k3), WAITVM(4));   // p7: tile 2j+2 landed
  }
  // ---- tail iter j=7 (tiles 14,15) ----
  {
    PHASE(0, 0, 0, true,  STA(1, 1, 15), {});
    PHASE(0, 1, 0, false, STB(1, 1, 15), {});
    PHASE(0, 0, 1, true,  {}, {});
    PHASE(0, 1, 1, false, {}, WAITVM(0));              // tile15 fully landed
    PHASE(1, 0, 0, true,  {}, {});
    PHASE(1, 1, 0, false, {}, {});
    PHASE(1, 0, 1, true,  {}, {});
    PHASE(1, 1, 1, false, {}, {});
  }
  __syncthreads();  // LDS reuse for epilogue

  if (MODE == 0) {
    int tsel = n0 >> 10, ncb = n0 & 1023;
    const float* bp = tsel == 0 ? b0 : (tsel == 1 ? b1 : b2);
    u16* outp = (u16*)outBase + (size_t)tsel * ((size_t)M_ROWS * E_DIM);
#pragma unroll
    for (int h = 0; h < 2; ++h) {
      if (h) __syncthreads();
      if (wm == h) {
#pragma unroll
        for (int nj = 0; nj < 4; nj++) {
          int cl = wn * 64 + nj * 16 + lr;
          float bb = bp[ncb + cl];
#pragma unroll
          for (int mi = 0; mi < 8; mi++) {
#pragma unroll
            for (int r = 0; r < 4; r++)
              epi[(mi * 16 + g * 4 + r) * 264 + cl] = f2b(acc[mi][nj][r] + bb);
          }
        }
      }
      __syncthreads();
      int row = t >> 2, c0 = (t & 3) * 64;
      int m = m0 + h * 128 + row;
      if (m < M) {
        u16* op = outp + (size_t)m * E_DIM + ncb + c0;
        const u16* lp = epi + row * 264 + c0;
#pragma unroll
        for (int qd = 0; qd < 8; qd++) ((uint4*)op)[qd] = ((const uint4*)lp)[qd];
      }
    }
  } else {
    float* outp = (float*)outBase;
#pragma unroll
    for (int nj = 0; nj < 4; nj++) {
      int n = n0 + wn * 64 + nj * 16 + lr;
      float bb = b0[n];
#pragma unroll
      for (int mi = 0; mi < 8; mi++) {
        int mb = m0 + wm * 128 + mi * 16 + g * 4;
#pragma unroll
        for (int r = 0; r < 4; r++)
          if (mb + r < M) outp[(size_t)(mb + r) * E_DIM + n] = acc[mi][nj][r] + bb;
      }
    }
  }
#undef STA
#undef STB
#undef RD_A
#undef RD_B
#undef MMROW
#undef PHASE
}

// distinct symbols so rocprof disambiguates the two GEMMs
__global__ __launch_bounds__(512, 1) void gemm8_qkv(const u16* __restrict__ A,
                                                    const u16* __restrict__ Wt,
                                                    const float* __restrict__ b0,
                                                    const float* __restrict__ b1,
                                                    const float* __restrict__ b2,
                                                    void* __restrict__ outBase,
                                                    int M, int NTIL) {
  gemm8_body<0>(A, Wt, b0, b1, b2, outBase, M, NTIL);
}
__global__ __launch_bounds__(512, 1) void gemm8_out(const u16* __restrict__ A,
                                                    const u16* __restrict__ Wt,
                                                    const float* __restrict__ b0,
                                                    const float* __restrict__ b1,
                                                    const float* __restrict__ b2,
                                                    void* __restrict__ outBase,
                                                    int M, int NTIL) {
  gemm8_body<1>(A, Wt, b0, b1, b2, outBase, M, NTIL);
}

// ---------------- global attention, phase 1: per-chunk partials ----------------
__global__ __launch_bounds__(256) void gattn1_kernel(const u16* __restrict__ Qb,
                                                     const u16* __restrict__ Kb,
                                                     const u16* __restrict__ Vb,
                                                     float* __restrict__ part) {
  int c = blockIdx.x;
  int h = blockIdx.y;
  int b = blockIdx.z;
  int t = threadIdx.x;
  __shared__ float qsh[64];
  __shared__ float red[4];
  __shared__ float psh[256];
  __shared__ float cred[4][64];

  size_t base = (size_t)b * L_TOT * E_DIM + h * 64;
  if (t < 64) qsh[t] = b2f(Qb[base + t]);
  __syncthreads();

  int row = c * 256 + t;
  bool valid = row < L_TOT;
  float dot = -1e30f;
  if (valid) {
    const u16* kp = Kb + base + (size_t)row * E_DIM;
    float acc = 0.f;
#pragma unroll
    for (int j = 0; j < 64; j += 8) {
      uint4 kv = *(const uint4*)(kp + j);
      const u16* kk = (const u16*)&kv;
#pragma unroll
      for (int q = 0; q < 8; q++) acc += qsh[j + q] * b2f(kk[q]);
    }
    dot = acc * 0.125f;
  }
  float m = dot;
  for (int mask = 1; mask < 64; mask <<= 1) m = fmaxf(m, __shfl_xor(m, mask));
  if ((t & 63) == 0) red[t >> 6] = m;
  __syncthreads();
  m = fmaxf(fmaxf(red[0], red[1]), fmaxf(red[2], red[3]));
  float p = valid ? __expf(dot - m) : 0.f;
  psh[t] = p;
  float s = p;
  for (int mask = 1; mask < 64; mask <<= 1) s += __shfl_xor(s, mask);
  __syncthreads();
  if ((t & 63) == 0) red[t >> 6] = s;
  __syncthreads();
  s = red[0] + red[1] + red[2] + red[3];

  int d = t & 63, gq = t >> 6;
  float acc = 0.f;
#pragma unroll 4
  for (int i = 0; i < 64; i++) {
    int sl = gq * 64 + i;
    int r2 = c * 256 + sl;
    if (r2 < L_TOT) acc += psh[sl] * b2f(Vb[base + (size_t)r2 * E_DIM + d]);
  }
  cred[gq][d] = acc;
  __syncthreads();
  if (t < 64) {
    float v = cred[0][t] + cred[1][t] + cred[2][t] + cred[3][t];
    float* pp = part + (((size_t)(b * HHEADS + h) * GCHUNKS + c) * 66);
    pp[t] = v;
    if (t == 0) { pp[64] = m; pp[65] = s; }
  }
}

// ---------------- global attention, phase 2: combine chunks ----------------
__global__ __launch_bounds__(64) void gattn2_kernel(const float* __restrict__ part,
                                                    u16* __restrict__ ctxb) {
  int bh = blockIdx.x;
  int b = bh >> 4, h = bh & 15;
  int d = threadIdx.x;
  const float* pp = part + ((size_t)(b * HHEADS + h) * GCHUNKS) * 66;
  float m = -1e30f;
#pragma unroll
  for (int c = 0; c < GCHUNKS; c++) m = fmaxf(m, pp[c * 66 + 64]);
  float stot = 0.f, acc = 0.f;
#pragma unroll
  for (int c = 0; c < GCHUNKS; c++) {
    float w = __expf(pp[c * 66 + 64] - m);
    stot += pp[c * 66 + 65] * w;
    acc += pp[c * 66 + d] * w;
  }
  ctxb[(size_t)b * L_TOT * E_DIM + h * 64 + d] = f2b(acc / stot);
}

// ========== windowed attention v2: swapped-QK^T, in-register softmax ==========
#define VT_IDX(d, k) ((d) * 264 + ((k) ^ ((((d) >> 3) & 7) << 3)))
__global__ __launch_bounds__(256) void wattn_kernel(const u16* __restrict__ Qb,
                                                    const u16* __restrict__ Kb,
                                                    const u16* __restrict__ Vb,
                                                    u16* __restrict__ winctx) {
  int wdw = blockIdx.x;
  int h = blockIdx.y;
  int b = blockIdx.z;

  __shared__ __align__(16) u16 Ks[256 * 64];   // 32 KB, GEMM-style swizzle
  __shared__ __align__(16) u16 Vt[64 * 264];   // 33 KB, [d][k] k-swizzled

  int t = threadIdx.x, lane = t & 63, wv = t >> 6;
  int g = lane >> 4, lr = lane & 15;
  size_t rowbase = (size_t)b * L_TOT + 1 + (size_t)wdw * 128;
  int hoff = h * 64;

  {
    int rsub = t >> 3;
    int ssrc = ((t & 7) ^ (rsub & 7)) * 8;
    const u16* kp = Kb + (rowbase + rsub) * E_DIM + hoff + ssrc;
#pragma unroll
    for (int c = 0; c < 8; c++)
      GLOAD16(kp + (size_t)c * 32 * E_DIM, Ks + c * 2048 + wv * 512);
  }
#pragma unroll
  for (int rep = 0; rep < 8; rep++) {
    int u = rep * 256 + t;
    int i = u >> 3;
    int d0 = (u & 7) * 8;
    uint4 v = *(const uint4*)(Vb + (rowbase + i) * E_DIM + hoff + d0);
    const u16* pv = (const u16*)&v;
#pragma unroll
    for (int j = 0; j < 8; j++) Vt[VT_IDX(d0 + j, i)] = pv[j];
  }
  __syncthreads();

  int slo = (2 * (g & 1)) * 16 + lr;
  int shi = slo + 16;

  for (int grp = 0; grp < 4; grp++) {
    int q0 = grp * 64 + wv * 16;
    const u16* qp = Qb + (rowbase + q0 + lr) * E_DIM + hoff;
    bf16x8 qa0 = *(const bf16x8*)(qp + g * 8);
    bf16x8 qa1 = *(const bf16x8*)(qp + 32 + g * 8);

    f4_t s[16];
    __builtin_amdgcn_s_setprio(1);
#pragma unroll
    for (int ki = 0; ki < 16; ki++) {
      int row = ki * 16 + lr;
      bf16x8 ka0 = *(const bf16x8*)&Ks[row * 64 + ((g ^ (lr & 7)) << 3)];
      bf16x8 ka1 = *(const bf16x8*)&Ks[row * 64 + (((4 + g) ^ (lr & 7)) << 3)];
      f4_t z = {};
      z = mfma16(ka0, qa0, z);
      z = mfma16(ka1, qa1, z);
      s[ki] = z;
    }
    __builtin_amdgcn_s_setprio(0);

    float mx = -1e30f;
#pragma unroll
    for (int ki = 0; ki < 16; ki++) {
      mx = fmaxf(mx, fmaxf(fmaxf(s[ki][0], s[ki][1]), fmaxf(s[ki][2], s[ki][3])));
    }
    mx = fmaxf(mx, __shfl_xor(mx, 16));
    mx = fmaxf(mx, __shfl_xor(mx, 32));
    float mx8 = mx * 0.125f;
    float sum = 0.f;
    u32 pk[16][2];
#pragma unroll
    for (int ki = 0; ki < 16; ki++) {
      float p0 = __expf(fmaf(s[ki][0], 0.125f, -mx8));
      float p1 = __expf(fmaf(s[ki][1], 0.125f, -mx8));
      float p2 = __expf(fmaf(s[ki][2], 0.125f, -mx8));
      float p3 = __expf(fmaf(s[ki][3], 0.125f, -mx8));
      sum += (p0 + p1) + (p2 + p3);
      pk[ki][0] = cvtpk(p0, p1);
      pk[ki][1] = cvtpk(p2, p3);
    }
    sum += __shfl_xor(sum, 16);
    sum += __shfl_xor(sum, 32);
    float inv = 1.0f / sum;

    u32 paw[8][4];
    bool hi = g >= 2;
#pragma unroll
    for (int kt = 0; kt < 8; kt++) {
      u32 v00 = __shfl((int)pk[kt * 2][0], slo);
      u32 v01 = __shfl((int)pk[kt * 2][1], slo);
      u32 v10 = __shfl((int)pk[kt * 2 + 1][0], slo);
      u32 v11 = __shfl((int)pk[kt * 2 + 1][1], slo);
      u32 w00 = __shfl((int)pk[kt * 2][0], shi);
      u32 w01 = __shfl((int)pk[kt * 2][1], shi);
      u32 w10 = __shfl((int)pk[kt * 2 + 1][0], shi);
      u32 w11 = __shfl((int)pk[kt * 2 + 1][1], shi);
      paw[kt][0] = hi ? v10 : v00;
      paw[kt][1] = hi ? v11 : v01;
      paw[kt][2] = hi ? w10 : w00;
      paw[kt][3] = hi ? w11 : w01;
    }

    f4_t o[4] = {};
    __builtin_amdgcn_s_setprio(1);
#pragma unroll
    for (int dtile = 0; dtile < 4; dtile++) {
      int d = dtile * 16 + lr;
      int dswz = (((d >> 3) & 7) << 3);
#pragma unroll
      for (int kt = 0; kt < 8; kt++) {
        int kphys = (kt * 32 + g * 8) ^ dswz;
        bf16x8 vb = *(const bf16x8*)&Vt[d * 264 + kphys];
        o[dtile] = mfma16(*(const bf16x8*)&paw[kt][0], vb, o[dtile]);
      }
    }
    __builtin_amdgcn_s_setprio(0);

    float invr[4];
#pragma unroll
    for (int r = 0; r < 4; r++) invr[r] = __shfl(inv, g * 4 + r);
    size_t orow = (size_t)(b * NWIN + wdw) * 256 + q0;
#pragma unroll
    for (int dtile = 0; dtile < 4; dtile++) {
#pragma unroll
      for (int r = 0; r < 4; r++) {
        winctx[(orow + g * 4 + r) * E_DIM + hoff + dtile * 16 + lr] =
            f2b(o[dtile][r] * invr[r]);
      }
    }
  }
}

// ---------------- overlap-average combine: winctx -> ctxb rows 1..4096 ----------------
__global__ __launch_bounds__(256) void combine_kernel(const u16* __restrict__ winctx,
                                                      u16* __restrict__ ctxb) {
  int idx = blockIdx.x * 256 + threadIdx.x;
  int e0 = (idx & 127) * 8;
  int p = (idx >> 7) & 4095;
  int b = idx >> 19;
  int whi = p >> 7;
  if (whi > 30) whi = 30;
  int off_hi = p - whi * 128;
  int wlo = whi - 1;
  bool has_lo = (wlo >= 0) && (off_hi < 128);

  uint4 vhi = *(const uint4*)(winctx + (((size_t)(b * NWIN + whi) * 256 + off_hi) * E_DIM) + e0);
  const u16* ph = (const u16*)&vhi;
  float vals[8];
#pragma unroll
  for (int j = 0; j < 8; j++) vals[j] = b2f(ph[j]);
  if (has_lo) {
    uint4 vlo = *(const uint4*)(winctx + (((size_t)(b * NWIN + wlo) * 256 + off_hi + 128) * E_DIM) + e0);
    const u16* pl = (const u16*)&vlo;
#pragma unroll
    for (int j = 0; j < 8; j++) vals[j] = (vals[j] + b2f(pl[j])) * 0.5f;
  }
  u16 out[8];
#pragma unroll
  for (int j = 0; j < 8; j++) out[j] = f2b(vals[j]);
  *(uint4*)(ctxb + ((size_t)b * L_TOT + 1 + p) * E_DIM + e0) = *(uint4*)out;
}

// ---------------- launch ----------------
extern "C" void kernel_launch(void* const* d_in, const int* in_sizes, int n_in,
                              void* d_out, int out_size, void* d_ws, size_t ws_size,
                              hipStream_t stream) {
  const float* hs = (const float*)d_in[0];
  const float* Wq = (const float*)d_in[1];
  const float* bq = (const float*)d_in[2];
  const float* Wk = (const float*)d_in[3];
  const float* bk = (const float*)d_in[4];
  const float* Wv = (const float*)d_in[5];
  const float* bv = (const float*)d_in[6];
  const float* Wo = (const float*)d_in[7];
  const float* bo = (const float*)d_in[8];

  const size_t BLE = (size_t)M_ROWS * E_DIM;
  const size_t BLE_B = BLE * 2;
  const size_t EE = (size_t)E_DIM * E_DIM;

  char* ws = (char*)d_ws;
  u16* hsb = (u16*)(ws);
  u16* wtb = (u16*)(ws + BLE_B);
  u16* qkv = (u16*)(ws + BLE_B + 4 * EE * 2);
  u16* Qb = qkv;
  u16* Kb = qkv + BLE;
  u16* Vb = qkv + 2 * BLE;
  u16* ctxb = (u16*)(ws + BLE_B + 4 * EE * 2 + 3 * BLE_B);
  u16* winctx = (u16*)(ws + BLE_B + 4 * EE * 2 + 4 * BLE_B);
  float* gpart = (float*)(ws + BLE_B + 4 * EE * 2 + 4 * BLE_B +
                          (size_t)B_SZ * NWIN * 256 * E_DIM * 2);

  cvt_kernel<<<8194, 256, 0, stream>>>(hs, hsb, (int)(BLE / 4));
  wtrans_kernel<<<dim3(32, 32, 4), dim3(32, 8), 0, stream>>>(Wq, Wk, Wv, Wo, wtb);
  // QKV fused: N = 3072 -> 33 m-tiles x 12 n-tiles = 396 blocks, 512 thr
  gemm8_qkv<<<33 * 12, 512, 0, stream>>>(hsb, wtb, bq, bk, bv, qkv, M_ROWS, 12);
  gattn1_kernel<<<dim3(GCHUNKS, HHEADS, B_SZ), 256, 0, stream>>>(Qb, Kb, Vb, gpart);
  gattn2_kernel<<<32, 64, 0, stream>>>(gpart, ctxb);
  wattn_kernel<<<dim3(NWIN, HHEADS, B_SZ), 256, 0, stream>>>(Qb, Kb, Vb, winctx);
  combine_kernel<<<4096, 256, 0, stream>>>(winctx, ctxb);
  // output projection: N = 1024 -> 33 x 4 = 132 blocks
  gemm8_out<<<33 * 4, 512, 0, stream>>>(ctxb, wtb + 3 * EE, bo, bo, bo, d_out, M_ROWS, 4);
}

// Round 11
// 215.044 us; speedup vs baseline: 1.0177x; 1.0177x over previous
//
#include <hip/hip_runtime.h>

typedef unsigned short u16;
typedef unsigned int u32;
typedef __bf16 bf16x8 __attribute__((ext_vector_type(8)));
typedef float f4_t __attribute__((ext_vector_type(4)));

#define E_DIM 1024
#define L_TOT 4097
#define B_SZ 2
#define M_ROWS 8194   // B*L
#define NWIN 31
#define HHEADS 16
#define GCHUNKS 17    // ceil(4097/256)

__device__ __forceinline__ float b2f(u16 v) {
  union { u32 u; float f; } x; x.u = ((u32)v) << 16; return x.f;
}
__device__ __forceinline__ u16 f2b(float f) {
  union { float f; u32 u; } x; x.f = f;
  u32 r = (x.u + 0x7FFFu + ((x.u >> 16) & 1u)) >> 16;
  return (u16)r;
}
__device__ __forceinline__ f4_t mfma16(bf16x8 a, bf16x8 b, f4_t c) {
  return __builtin_amdgcn_mfma_f32_16x16x32_bf16(a, b, c, 0, 0, 0);
}
__device__ __forceinline__ u32 cvtpk(float lo, float hi) {
  u32 r;
  asm volatile("v_cvt_pk_bf16_f32 %0, %1, %2" : "=v"(r) : "v"(lo), "v"(hi));
  return r;
}

// async global->LDS, 16B per lane; LDS dest = wave-uniform base + lane*16
#define GLOAD16(gp, lp)                                                              \
  __builtin_amdgcn_global_load_lds(                                                  \
      (const __attribute__((address_space(1))) u32*)(gp),                            \
      (__attribute__((address_space(3))) u32*)(lp), 16, 0, 0)

#define WAITVM(N) asm volatile("s_waitcnt vmcnt(" #N ")" ::: "memory")

// ---------------- fp32 -> bf16 convert (hidden states) ----------------
__global__ __launch_bounds__(256) void cvt_kernel(const float* __restrict__ src,
                                                  u16* __restrict__ dst, int n4) {
  int i = blockIdx.x * 256 + threadIdx.x;
  if (i >= n4) return;
  float4 v = ((const float4*)src)[i];
  u16 o[4] = {f2b(v.x), f2b(v.y), f2b(v.z), f2b(v.w)};
  *(uint2*)(dst + (size_t)i * 4) = *(uint2*)o;
}

// ---------------- weight transpose + convert: W (K x N) -> Wt (N x K) bf16 ----------------
__global__ __launch_bounds__(256) void wtrans_kernel(const float* __restrict__ w0,
                                                     const float* __restrict__ w1,
                                                     const float* __restrict__ w2,
                                                     const float* __restrict__ w3,
                                                     u16* __restrict__ wtb) {
  const float* src = blockIdx.z == 0 ? w0 : blockIdx.z == 1 ? w1 : blockIdx.z == 2 ? w2 : w3;
  u16* dst = wtb + (size_t)blockIdx.z * E_DIM * E_DIM;
  __shared__ float tile[32][33];
  int tx = threadIdx.x, ty = threadIdx.y;
  int x = blockIdx.x * 32 + tx;
  int y0 = blockIdx.y * 32;
  for (int j = ty; j < 32; j += 8) tile[j][tx] = src[(size_t)(y0 + j) * E_DIM + x];
  __syncthreads();
  for (int j = ty; j < 32; j += 8)
    dst[(size_t)(blockIdx.x * 32 + j) * E_DIM + blockIdx.y * 32 + tx] = f2b(tile[tx][j]);
}

// ============ GEMM r11: 128x128 tile, BK=32, dbuf 32KB LDS, 4 blocks/CU ============
// C(M x NTIL*128) = A(M x 1024) * Wt^T + bias; Wt stored [N][1024].
// 256 thr = 4 waves (2M x 2N), per-wave 64x64 out, acc[4][4].
// LDS [2 buf][128][32] u16 per operand (32 KB) -> 4-5 blocks/CU; m114 cross-block
// overlap hides barriers/LDS gaps. Counted vmcnt, 1-ahead staging: DMA for K-step
// ks+2 issued at iter ks -> full iteration of latency hiding; in-flight <= 8;
// WAITVM(4) per iter (never 0 mid-loop).
// Swizzle (64-B rows): read phys slot = g ^ ((lr>>1)&3) -> 2-way bank alias (free,
// m136); staging source col inverse-swizzled, DMA dest linear (rule #21).
// Race-free: mid __syncthreads separates frag reads (lgkm-drained) from DMA
// overwrite of same buffer; end WAITVM+s_barrier ensures ALL waves' DMA for the
// next buffer landed before any wave reads it.
template <int MODE>
__device__ __forceinline__ void gemmC_body(const u16* __restrict__ A,
                                           const u16* __restrict__ Wt,
                                           const float* __restrict__ b0,
                                           const float* __restrict__ b1,
                                           const float* __restrict__ b2,
                                           void* __restrict__ outBase,
                                           int M, int NTIL) {
  __shared__ __align__(16) char smraw[34816];  // stage 32 KB; epilogue 34 KB alias
  u16* sA = (u16*)smraw;            // [2][128][32] u16 = 16 KB
  u16* sB = sA + 2 * 4096;          // 16 KB
  u16* epi16 = (u16*)smraw;         // [128][136] u16 (MODE 0)
  float* epi32 = (float*)smraw;     // [128][68] f32 (MODE 1, 2 passes)

  // bijective XCD swizzle (nwg % 8 == 0), nt-fast for A-panel L2 reuse
  int nwg = gridDim.x;
  int cpx = nwg >> 3;
  int orig = blockIdx.x;
  int wg = (orig & 7) * cpx + (orig >> 3);
  int mt = wg / NTIL, nt = wg - mt * NTIL;
  int m0 = mt * 128, n0 = nt * 128;

  int t = threadIdx.x, lane = t & 63, w = t >> 6;
  int wr = w >> 1, wc = w & 1;
  int lr = lane & 15, g = lane >> 4;

  // staging: load round c (c=0,1) covers rows [c*64, c*64+64); thread t -> row
  // c*64 + (t>>2), phys slot t&3; source logical slot = (t&3) ^ (((t>>2)>>1)&3)
  int ssrc = (((t & 3) ^ ((t >> 3) & 3)) << 3);
  const u16* pa[2];
  const u16* pb[2];
#pragma unroll
  for (int c = 0; c < 2; c++) {
    int ra = m0 + c * 64 + (t >> 2);
    if (ra >= M) ra = M - 1;
    pa[c] = A + (size_t)ra * 1024 + ssrc;
    pb[c] = Wt + (size_t)(n0 + c * 64 + (t >> 2)) * 1024 + ssrc;
  }
  int wb = w * 512;  // wave-uniform u16 offset; lane adds 16B

#define STAGE(bf, ks)                                              \
  {                                                                \
    GLOAD16(pa[0] + (ks) * 32, sA + (bf) * 4096 + wb);             \
    GLOAD16(pa[1] + (ks) * 32, sA + (bf) * 4096 + 2048 + wb);      \
    GLOAD16(pb[0] + (ks) * 32, sB + (bf) * 4096 + wb);             \
    GLOAD16(pb[1] + (ks) * 32, sB + (bf) * 4096 + 2048 + wb);      \
  }

  int swz = ((g ^ ((lr >> 1) & 3)) << 3);  // u16 offset within 32-u16 row
  int arow0 = wr * 64 + lr;
  int brow0 = wc * 64 + lr;

  f4_t acc[4][4] = {};

  // prologue: K-steps 0,1 in flight
  STAGE(0, 0);
  STAGE(1, 1);
  WAITVM(4);                          // ks0 landed (per-wave)
  __builtin_amdgcn_s_barrier();       // all waves' ks0 DMA landed
  __builtin_amdgcn_sched_barrier(0);

#pragma unroll 2
  for (int ks = 0; ks < 32; ++ks) {
    int bf = ks & 1;
    int base = bf * 4096;
    bf16x8 av[4], bv[4];
#pragma unroll
    for (int i = 0; i < 4; i++)
      av[i] = *(const bf16x8*)&sA[base + (arow0 + i * 16) * 32 + swz];
#pragma unroll
    for (int j = 0; j < 4; j++)
      bv[j] = *(const bf16x8*)&sB[base + (brow0 + j * 16) * 32 + swz];
    __syncthreads();                  // frag reads complete (lgkm) across block
    if (ks < 30) STAGE(bf, ks + 2);   // refill just-read buffer, 2 steps ahead
    __builtin_amdgcn_sched_barrier(0);
    __builtin_amdgcn_s_setprio(1);
#pragma unroll
    for (int i = 0; i < 4; i++)
#pragma unroll
      for (int j = 0; j < 4; j++) acc[i][j] = mfma16(av[i], bv[j], acc[i][j]);
    __builtin_amdgcn_s_setprio(0);
    if (ks < 30) {
      WAITVM(4);                      // ks+1's 4 DMA landed; ks+2's stay in flight
    } else if (ks == 30) {
      WAITVM(0);                      // ks31 fully landed
    }
    if (ks < 31) {
      __builtin_amdgcn_s_barrier();   // all waves' DMA for next buffer landed
      __builtin_amdgcn_sched_barrier(0);
    }
  }
  __syncthreads();  // protect LDS before epilogue aliasing

  // ---------------- coalesced epilogue via LDS ----------------
  if (MODE == 0) {
    int tsel = n0 >> 10, ncb = n0 & 1023;
    const float* bp = tsel == 0 ? b0 : (tsel == 1 ? b1 : b2);
#pragma unroll
    for (int j = 0; j < 4; j++) {
      int ncl = wc * 64 + j * 16 + lr;
      float bb = bp[ncb + ncl];
#pragma unroll
      for (int i = 0; i < 4; i++) {
        int mlb = wr * 64 + i * 16 + g * 4;
#pragma unroll
        for (int r = 0; r < 4; r++) epi16[(mlb + r) * 136 + ncl] = f2b(acc[i][j][r] + bb);
      }
    }
    __syncthreads();
    int row = t >> 1, half = t & 1;
    int m = m0 + row;
    if (m < M) {
      u16* op = (u16*)outBase + (size_t)tsel * ((size_t)M_ROWS * E_DIM) + (size_t)m * E_DIM + ncb + half * 64;
      const u16* lp = epi16 + row * 136 + half * 64;
#pragma unroll
      for (int qd = 0; qd < 8; qd++) ((uint4*)op)[qd] = ((const uint4*)lp)[qd];
    }
  } else {
#pragma unroll
    for (int p = 0; p < 2; p++) {
      if (p) __syncthreads();
      if (wc == p) {
#pragma unroll
        for (int j = 0; j < 4; j++) {
          int ncl = j * 16 + lr;
          float bb = b0[n0 + p * 64 + ncl];
#pragma unroll
          for (int i = 0; i < 4; i++) {
            int mlb = wr * 64 + i * 16 + g * 4;
#pragma unroll
            for (int r = 0; r < 4; r++) epi32[(mlb + r) * 68 + ncl] = acc[i][j][r] + bb;
          }
        }
      }
      __syncthreads();
      int row = t >> 1, qr = t & 1;
      int m = m0 + row;
      if (m < M) {
        float* op = (float*)outBase + (size_t)m * E_DIM + n0 + p * 64 + qr * 32;
        const float* lp = epi32 + row * 68 + qr * 32;
#pragma unroll
        for (int qd = 0; qd < 8; qd++) ((float4*)op)[qd] = ((const float4*)lp)[qd];
      }
    }
  }
#undef STAGE
}

// distinct symbols so rocprof disambiguates
__global__ __launch_bounds__(256, 4) void gemmC_qkv(const u16* __restrict__ A,
                                                    const u16* __restrict__ Wt,
                                                    const float* __restrict__ b0,
                                                    const float* __restrict__ b1,
                                                    const float* __restrict__ b2,
                                                    void* __restrict__ outBase,
                                                    int M, int NTIL) {
  gemmC_body<0>(A, Wt, b0, b1, b2, outBase, M, NTIL);
}
__global__ __launch_bounds__(256, 4) void gemmC_out(const u16* __restrict__ A,
                                                    const u16* __restrict__ Wt,
                                                    const float* __restrict__ b0,
                                                    const float* __restrict__ b1,
                                                    const float* __restrict__ b2,
                                                    void* __restrict__ outBase,
                                                    int M, int NTIL) {
  gemmC_body<1>(A, Wt, b0, b1, b2, outBase, M, NTIL);
}

// ---------------- global attention, phase 1: per-chunk partials ----------------
__global__ __launch_bounds__(256) void gattn1_kernel(const u16* __restrict__ Qb,
                                                     const u16* __restrict__ Kb,
                                                     const u16* __restrict__ Vb,
                                                     float* __restrict__ part) {
  int c = blockIdx.x;
  int h = blockIdx.y;
  int b = blockIdx.z;
  int t = threadIdx.x;
  __shared__ float qsh[64];
  __shared__ float red[4];
  __shared__ float psh[256];
  __shared__ float cred[4][64];

  size_t base = (size_t)b * L_TOT * E_DIM + h * 64;
  if (t < 64) qsh[t] = b2f(Qb[base + t]);
  __syncthreads();

  int row = c * 256 + t;
  bool valid = row < L_TOT;
  float dot = -1e30f;
  if (valid) {
    const u16* kp = Kb + base + (size_t)row * E_DIM;
    float acc = 0.f;
#pragma unroll
    for (int j = 0; j < 64; j += 8) {
      uint4 kv = *(const uint4*)(kp + j);
      const u16* kk = (const u16*)&kv;
#pragma unroll
      for (int q = 0; q < 8; q++) acc += qsh[j + q] * b2f(kk[q]);
    }
    dot = acc * 0.125f;
  }
  float m = dot;
  for (int mask = 1; mask < 64; mask <<= 1) m = fmaxf(m, __shfl_xor(m, mask));
  if ((t & 63) == 0) red[t >> 6] = m;
  __syncthreads();
  m = fmaxf(fmaxf(red[0], red[1]), fmaxf(red[2], red[3]));
  float p = valid ? __expf(dot - m) : 0.f;
  psh[t] = p;
  float s = p;
  for (int mask = 1; mask < 64; mask <<= 1) s += __shfl_xor(s, mask);
  __syncthreads();
  if ((t & 63) == 0) red[t >> 6] = s;
  __syncthreads();
  s = red[0] + red[1] + red[2] + red[3];

  int d = t & 63, gq = t >> 6;
  float acc = 0.f;
#pragma unroll 4
  for (int i = 0; i < 64; i++) {
    int sl = gq * 64 + i;
    int r2 = c * 256 + sl;
    if (r2 < L_TOT) acc += psh[sl] * b2f(Vb[base + (size_t)r2 * E_DIM + d]);
  }
  cred[gq][d] = acc;
  __syncthreads();
  if (t < 64) {
    float v = cred[0][t] + cred[1][t] + cred[2][t] + cred[3][t];
    float* pp = part + (((size_t)(b * HHEADS + h) * GCHUNKS + c) * 66);
    pp[t] = v;
    if (t == 0) { pp[64] = m; pp[65] = s; }
  }
}

// ---------------- global attention, phase 2: combine chunks ----------------
__global__ __launch_bounds__(64) void gattn2_kernel(const float* __restrict__ part,
                                                    u16* __restrict__ ctxb) {
  int bh = blockIdx.x;
  int b = bh >> 4, h = bh & 15;
  int d = threadIdx.x;
  const float* pp = part + ((size_t)(b * HHEADS + h) * GCHUNKS) * 66;
  float m = -1e30f;
#pragma unroll
  for (int c = 0; c < GCHUNKS; c++) m = fmaxf(m, pp[c * 66 + 64]);
  float stot = 0.f, acc = 0.f;
#pragma unroll
  for (int c = 0; c < GCHUNKS; c++) {
    float w = __expf(pp[c * 66 + 64] - m);
    stot += pp[c * 66 + 65] * w;
    acc += pp[c * 66 + d] * w;
  }
  ctxb[(size_t)b * L_TOT * E_DIM + h * 64 + d] = f2b(acc / stot);
}

// ========== windowed attention v2: swapped-QK^T, in-register softmax ==========
#define VT_IDX(d, k) ((d) * 264 + ((k) ^ ((((d) >> 3) & 7) << 3)))
__global__ __launch_bounds__(256) void wattn_kernel(const u16* __restrict__ Qb,
                                                    const u16* __restrict__ Kb,
                                                    const u16* __restrict__ Vb,
                                                    u16* __restrict__ winctx) {
  int wdw = blockIdx.x;
  int h = blockIdx.y;
  int b = blockIdx.z;

  __shared__ __align__(16) u16 Ks[256 * 64];   // 32 KB, GEMM-style swizzle
  __shared__ __align__(16) u16 Vt[64 * 264];   // 33 KB, [d][k] k-swizzled

  int t = threadIdx.x, lane = t & 63, wv = t >> 6;
  int g = lane >> 4, lr = lane & 15;
  size_t rowbase = (size_t)b * L_TOT + 1 + (size_t)wdw * 128;
  int hoff = h * 64;

  {
    int rsub = t >> 3;
    int ssrc = ((t & 7) ^ (rsub & 7)) * 8;
    const u16* kp = Kb + (rowbase + rsub) * E_DIM + hoff + ssrc;
#pragma unroll
    for (int c = 0; c < 8; c++)
      GLOAD16(kp + (size_t)c * 32 * E_DIM, Ks + c * 2048 + wv * 512);
  }
#pragma unroll
  for (int rep = 0; rep < 8; rep++) {
    int u = rep * 256 + t;
    int i = u >> 3;
    int d0 = (u & 7) * 8;
    uint4 v = *(const uint4*)(Vb + (rowbase + i) * E_DIM + hoff + d0);
    const u16* pv = (const u16*)&v;
#pragma unroll
    for (int j = 0; j < 8; j++) Vt[VT_IDX(d0 + j, i)] = pv[j];
  }
  __syncthreads();

  int slo = (2 * (g & 1)) * 16 + lr;
  int shi = slo + 16;

  for (int grp = 0; grp < 4; grp++) {
    int q0 = grp * 64 + wv * 16;
    const u16* qp = Qb + (rowbase + q0 + lr) * E_DIM + hoff;
    bf16x8 qa0 = *(const bf16x8*)(qp + g * 8);
    bf16x8 qa1 = *(const bf16x8*)(qp + 32 + g * 8);

    f4_t s[16];
    __builtin_amdgcn_s_setprio(1);
#pragma unroll
    for (int ki = 0; ki < 16; ki++) {
      int row = ki * 16 + lr;
      bf16x8 ka0 = *(const bf16x8*)&Ks[row * 64 + ((g ^ (lr & 7)) << 3)];
      bf16x8 ka1 = *(const bf16x8*)&Ks[row * 64 + (((4 + g) ^ (lr & 7)) << 3)];
      f4_t z = {};
      z = mfma16(ka0, qa0, z);
      z = mfma16(ka1, qa1, z);
      s[ki] = z;
    }
    __builtin_amdgcn_s_setprio(0);

    float mx = -1e30f;
#pragma unroll
    for (int ki = 0; ki < 16; ki++) {
      mx = fmaxf(mx, fmaxf(fmaxf(s[ki][0], s[ki][1]), fmaxf(s[ki][2], s[ki][3])));
    }
    mx = fmaxf(mx, __shfl_xor(mx, 16));
    mx = fmaxf(mx, __shfl_xor(mx, 32));
    float mx8 = mx * 0.125f;
    float sum = 0.f;
    u32 pk[16][2];
#pragma unroll
    for (int ki = 0; ki < 16; ki++) {
      float p0 = __expf(fmaf(s[ki][0], 0.125f, -mx8));
      float p1 = __expf(fmaf(s[ki][1], 0.125f, -mx8));
      float p2 = __expf(fmaf(s[ki][2], 0.125f, -mx8));
      float p3 = __expf(fmaf(s[ki][3], 0.125f, -mx8));
      sum += (p0 + p1) + (p2 + p3);
      pk[ki][0] = cvtpk(p0, p1);
      pk[ki][1] = cvtpk(p2, p3);
    }
    sum += __shfl_xor(sum, 16);
    sum += __shfl_xor(sum, 32);
    float inv = 1.0f / sum;

    u32 paw[8][4];
    bool hi = g >= 2;
#pragma unroll
    for (int kt = 0; kt < 8; kt++) {
      u32 v00 = __shfl((int)pk[kt * 2][0], slo);
      u32 v01 = __shfl((int)pk[kt * 2][1], slo);
      u32 v10 = __shfl((int)pk[kt * 2 + 1][0], slo);
      u32 v11 = __shfl((int)pk[kt * 2 + 1][1], slo);
      u32 w00 = __shfl((int)pk[kt * 2][0], shi);
      u32 w01 = __shfl((int)pk[kt * 2][1], shi);
      u32 w10 = __shfl((int)pk[kt * 2 + 1][0], shi);
      u32 w11 = __shfl((int)pk[kt * 2 + 1][1], shi);
      paw[kt][0] = hi ? v10 : v00;
      paw[kt][1] = hi ? v11 : v01;
      paw[kt][2] = hi ? w10 : w00;
      paw[kt][3] = hi ? w11 : w01;
    }

    f4_t o[4] = {};
    __builtin_amdgcn_s_setprio(1);
#pragma unroll
    for (int dtile = 0; dtile < 4; dtile++) {
      int d = dtile * 16 + lr;
      int dswz = (((d >> 3) & 7) << 3);
#pragma unroll
      for (int kt = 0; kt < 8; kt++) {
        int kphys = (kt * 32 + g * 8) ^ dswz;
        bf16x8 vb = *(const bf16x8*)&Vt[d * 264 + kphys];
        o[dtile] = mfma16(*(const bf16x8*)&paw[kt][0], vb, o[dtile]);
      }
    }
    __builtin_amdgcn_s_setprio(0);

    float invr[4];
#pragma unroll
    for (int r = 0; r < 4; r++) invr[r] = __shfl(inv, g * 4 + r);
    size_t orow = (size_t)(b * NWIN + wdw) * 256 + q0;
#pragma unroll
    for (int dtile = 0; dtile < 4; dtile++) {
#pragma unroll
      for (int r = 0; r < 4; r++) {
        winctx[(orow + g * 4 + r) * E_DIM + hoff + dtile * 16 + lr] =
            f2b(o[dtile][r] * invr[r]);
      }
    }
  }
}

// ---------------- overlap-average combine: winctx -> ctxb rows 1..4096 ----------------
__global__ __launch_bounds__(256) void combine_kernel(const u16* __restrict__ winctx,
                                                      u16* __restrict__ ctxb) {
  int idx = blockIdx.x * 256 + threadIdx.x;
  int e0 = (idx & 127) * 8;
  int p = (idx >> 7) & 4095;
  int b = idx >> 19;
  int whi = p >> 7;
  if (whi > 30) whi = 30;
  int off_hi = p - whi * 128;
  int wlo = whi - 1;
  bool has_lo = (wlo >= 0) && (off_hi < 128);

  uint4 vhi = *(const uint4*)(winctx + (((size_t)(b * NWIN + whi) * 256 + off_hi) * E_DIM) + e0);
  const u16* ph = (const u16*)&vhi;
  float vals[8];
#pragma unroll
  for (int j = 0; j < 8; j++) vals[j] = b2f(ph[j]);
  if (has_lo) {
    uint4 vlo = *(const uint4*)(winctx + (((size_t)(b * NWIN + wlo) * 256 + off_hi + 128) * E_DIM) + e0);
    const u16* pl = (const u16*)&vlo;
#pragma unroll
    for (int j = 0; j < 8; j++) vals[j] = (vals[j] + b2f(pl[j])) * 0.5f;
  }
  u16 out[8];
#pragma unroll
  for (int j = 0; j < 8; j++) out[j] = f2b(vals[j]);
  *(uint4*)(ctxb + ((size_t)b * L_TOT + 1 + p) * E_DIM + e0) = *(uint4*)out;
}

// ---------------- launch ----------------
extern "C" void kernel_launch(void* const* d_in, const int* in_sizes, int n_in,
                              void* d_out, int out_size, void* d_ws, size_t ws_size,
                              hipStream_t stream) {
  const float* hs = (const float*)d_in[0];
  const float* Wq = (const float*)d_in[1];
  const float* bq = (const float*)d_in[2];
  const float* Wk = (const float*)d_in[3];
  const float* bk = (const float*)d_in[4];
  const float* Wv = (const float*)d_in[5];
  const float* bv = (const float*)d_in[6];
  const float* Wo = (const float*)d_in[7];
  const float* bo = (const float*)d_in[8];

  const size_t BLE = (size_t)M_ROWS * E_DIM;
  const size_t BLE_B = BLE * 2;
  const size_t EE = (size_t)E_DIM * E_DIM;

  char* ws = (char*)d_ws;
  u16* hsb = (u16*)(ws);
  u16* wtb = (u16*)(ws + BLE_B);
  u16* qkv = (u16*)(ws + BLE_B + 4 * EE * 2);
  u16* Qb = qkv;
  u16* Kb = qkv + BLE;
  u16* Vb = qkv + 2 * BLE;
  u16* ctxb = (u16*)(ws + BLE_B + 4 * EE * 2 + 3 * BLE_B);
  u16* winctx = (u16*)(ws + BLE_B + 4 * EE * 2 + 4 * BLE_B);
  float* gpart = (float*)(ws + BLE_B + 4 * EE * 2 + 4 * BLE_B +
                          (size_t)B_SZ * NWIN * 256 * E_DIM * 2);

  cvt_kernel<<<8194, 256, 0, stream>>>(hs, hsb, (int)(BLE / 4));
  wtrans_kernel<<<dim3(32, 32, 4), dim3(32, 8), 0, stream>>>(Wq, Wk, Wv, Wo, wtb);
  // QKV fused: N = 3072 -> 65 m-tiles x 24 n-tiles = 1560 blocks
  gemmC_qkv<<<65 * 24, 256, 0, stream>>>(hsb, wtb, bq, bk, bv, qkv, M_ROWS, 24);
  gattn1_kernel<<<dim3(GCHUNKS, HHEADS, B_SZ), 256, 0, stream>>>(Qb, Kb, Vb, gpart);
  gattn2_kernel<<<32, 64, 0, stream>>>(gpart, ctxb);
  wattn_kernel<<<dim3(NWIN, HHEADS, B_SZ), 256, 0, stream>>>(Qb, Kb, Vb, winctx);
  combine_kernel<<<4096, 256, 0, stream>>>(winctx, ctxb);
  // output projection: N = 1024 -> 65 x 8 = 520 blocks
  gemmC_out<<<65 * 8, 256, 0, stream>>>(ctxb, wtb + 3 * EE, bo, bo, bo, d_out, M_ROWS, 8);
}